// Round 8
// baseline (321.154 us; speedup 1.0000x reference)
//
#include <hip/hip_runtime.h>

typedef __attribute__((ext_vector_type(4))) float f32x4;

#define NT 256
#define S 10
#define D 100
#define H 16
#define NITER 5
#define RQ 25   // LDS out-staging row stride in quads (24 used + 1 pad)
#define OUTQ 24 // quads per output row (6*16 floats)

// Volatile LDS weight reads: forbids LICM/CSE from promoting the whole
// W_k (64 quads = 256 VGPRs!) / W_proj (400 quads) tiles into registers.
// That promotion is what pegged VGPR at 256 and spilled the ic state in
// rounds 1-7 (spill signature: ~150-550 MB of excess HBM writes).
#define VLOAD(arr, idx) (*(volatile const f32x4*)&(arr)[(idx)])

__global__ __launch_bounds__(NT, 1)
void attn_greedy_kernel(const float* __restrict__ user_intent,
                        const float* __restrict__ item_corpus,
                        const float* __restrict__ W_proj,
                        const float* __restrict__ b_proj,
                        const float* __restrict__ W_k,
                        const float* __restrict__ b_k,
                        float* __restrict__ out)
{
    // Weights: wave-uniform broadcast reads (conflict-free).
    __shared__ f32x4 s_wp[D * 4];     // wp[d][q], 6400 B
    __shared__ f32x4 s_wk[H * 4];     // wk[k][q], 1024 B
    __shared__ f32x4 s_bp[4];
    __shared__ f32x4 s_bk[4];
    __shared__ f32x4 s_out[NT * RQ];  // 100 KB out staging

    {
        float* wpf = (float*)s_wp;
        for (int i = threadIdx.x; i < D * H; i += NT) wpf[i] = W_proj[i];
        float* wkf = (float*)s_wk;
        for (int i = threadIdx.x; i < H * H; i += NT) wkf[i] = W_k[i];
        if (threadIdx.x < H) {
            ((float*)s_bp)[threadIdx.x] = b_proj[threadIdx.x];
            ((float*)s_bk)[threadIdx.x] = b_k[threadIdx.x];
        }
    }
    __syncthreads();

    const int t = threadIdx.x;
    const size_t b = (size_t)blockIdx.x * NT + t;   // one row per thread
    const f32x4* crow = (const f32x4*)item_corpus + b * (S * D / 4);

    // user_intent: one full 64B line per lane; stash in s_out row 0..3 now.
    const f32x4* urow = (const f32x4*)user_intent + b * 4;
    f32x4 usum[4];
    #pragma unroll
    for (int q = 0; q < 4; ++q) {
        f32x4 u = urow[q];
        usum[q] = u;
        s_out[t * RQ + q] = u;
    }

    // ---- Projection: s OUTER, i INNER -> each lane streams its row
    // sequentially (1 live cache line per lane -> L1-resident).
    // Weight reads volatile: re-read from LDS per s instead of being
    // register-promoted across the unrolled s-loop.
    f32x4 ic[S][4];
    #pragma unroll
    for (int s = 0; s < S; ++s) {
        f32x4 a0 = s_bp[0], a1 = s_bp[1], a2 = s_bp[2], a3 = s_bp[3];
        #pragma unroll 5
        for (int i = 0; i < D / 4; ++i) {
            f32x4 c = crow[s * (D / 4) + i];
            #pragma unroll
            for (int dd = 0; dd < 4; ++dd) {
                float a = c[dd];
                const int wbase = (i * 4 + dd) * 4;
                f32x4 w0 = VLOAD(s_wp, wbase + 0);
                f32x4 w1 = VLOAD(s_wp, wbase + 1);
                f32x4 w2 = VLOAD(s_wp, wbase + 2);
                f32x4 w3 = VLOAD(s_wp, wbase + 3);
                a0 += a * w0;
                a1 += a * w1;
                a2 += a * w2;
                a3 += a * w3;
            }
        }
        ic[s][0] = a0; ic[s][1] = a1; ic[s][2] = a2; ic[s][3] = a3;
    }

    // ---- Greedy iterations. unroll 1: keep one copy of the body so the
    // volatile wk reads stay at 640/iteration and code stays compact.
    #pragma unroll 1
    for (int it = 0; it < NITER; ++it) {
        // ic = ic @ Wk + bk, per-s IN PLACE, k ascending (same accumulation
        // order as all passing rounds -> bit-identical).
        #pragma unroll
        for (int s = 0; s < S; ++s) {
            f32x4 n0 = s_bk[0], n1 = s_bk[1], n2 = s_bk[2], n3 = s_bk[3];
            #pragma unroll
            for (int k = 0; k < H; ++k) {
                float a = ic[s][k >> 2][k & 3];
                f32x4 w0 = VLOAD(s_wk, k * 4 + 0);
                f32x4 w1 = VLOAD(s_wk, k * 4 + 1);
                f32x4 w2 = VLOAD(s_wk, k * 4 + 2);
                f32x4 w3 = VLOAD(s_wk, k * 4 + 3);
                n0 += a * w0;
                n1 += a * w1;
                n2 += a * w2;
                n3 += a * w3;
            }
            ic[s][0] = n0; ic[s][1] = n1; ic[s][2] = n2; ic[s][3] = n3;
        }

        // src = mean(ui)
        float cnt = (float)(it + 1);
        f32x4 src[4];
        #pragma unroll
        for (int q = 0; q < 4; ++q) src[q] = usum[q] / cnt;

        // scores + first-max argmax (softmax skipped: monotonic)
        float best = 0.0f;
        int bidx = 0;
        #pragma unroll
        for (int s = 0; s < S; ++s) {
            float sc = 0.0f;
            #pragma unroll
            for (int q = 0; q < 4; ++q)
                #pragma unroll
                for (int c = 0; c < 4; ++c)
                    sc += ic[s][q][c] * src[q][c];
            if (s == 0 || sc > best) { best = sc; bidx = s; }
        }

        // item_vec = ic[bidx] via unrolled select (static register indexing)
        f32x4 iv[4];
        #pragma unroll
        for (int q = 0; q < 4; ++q) iv[q] = ic[0][q];
        #pragma unroll
        for (int s = 1; s < S; ++s) {
            bool take = (bidx == s);
            #pragma unroll
            for (int q = 0; q < 4; ++q)
                iv[q] = take ? ic[s][q] : iv[q];
        }

        #pragma unroll
        for (int q = 0; q < 4; ++q) {
            usum[q] += iv[q];
            s_out[t * RQ + (it + 1) * 4 + q] = iv[q];
        }
    }

    // ---- Coalesced output: block region is contiguous 96 KB; lanes store
    // consecutive 16B -> full-line writes only.
    __syncthreads();
    f32x4* out4 = (f32x4*)out;
    const size_t obase = (size_t)blockIdx.x * NT * OUTQ;
    #pragma unroll
    for (int k = 0; k < OUTQ; ++k) {
        int j = t + k * NT;
        int row = j / OUTQ;
        int q = j - row * OUTQ;
        out4[obase + j] = s_out[row * RQ + q];
    }
}

extern "C" void kernel_launch(void* const* d_in, const int* in_sizes, int n_in,
                              void* d_out, int out_size, void* d_ws, size_t ws_size,
                              hipStream_t stream) {
    const float* user_intent = (const float*)d_in[0];
    const float* item_corpus = (const float*)d_in[1];
    const float* W_proj      = (const float*)d_in[2];
    const float* b_proj      = (const float*)d_in[3];
    const float* W_k         = (const float*)d_in[4];
    const float* b_k         = (const float*)d_in[5];
    float* out = (float*)d_out;

    const int bs = 65536;
    hipLaunchKernelGGL(attn_greedy_kernel,
                       dim3(bs / NT), dim3(NT), 0, stream,
                       user_intent, item_corpus, W_proj, b_proj, W_k, b_k, out);
}

// Round 9
// 143.815 us; speedup vs baseline: 2.2331x; 2.2331x over previous
//
#include <hip/hip_runtime.h>

typedef __attribute__((ext_vector_type(4))) float f32x4;

#define NT 256
#define S 10
#define SL 5                    // corpus rows per lane in search kernel
#define D 100
#define H 16
#define NITER 5
#define RPB (NT / 2)            // batch rows per block in search kernel = 128
#define RQ 25                   // LDS out-staging row stride in quads (24 + 1 pad)
#define OUTQ 24                 // quads per output row (6*16 floats)
#define WS_NEEDED ((size_t)65536 * S * H * 4)   // 41.9 MB ic buffer

// ================= Kernel A: projection (streaming) =================
// One thread per corpus row (b*10+s == gid): 400B sequential read,
// 64B coalesced write. No per-thread state array -> no spill; verified
// near-roofline in round 7.
__global__ __launch_bounds__(NT, 1)
void proj_kernel(const float* __restrict__ item_corpus,
                 const float* __restrict__ W_proj,
                 const float* __restrict__ b_proj,
                 float* __restrict__ ic_ws)
{
    __shared__ f32x4 s_wp[D * 4];   // wp[d][q], broadcast reads
    __shared__ f32x4 s_bp[4];
    {
        float* wpf = (float*)s_wp;
        for (int i = threadIdx.x; i < D * H; i += NT) wpf[i] = W_proj[i];
        if (threadIdx.x < H) ((float*)s_bp)[threadIdx.x] = b_proj[threadIdx.x];
    }
    __syncthreads();

    const size_t gid = (size_t)blockIdx.x * NT + threadIdx.x;
    const f32x4* crow = (const f32x4*)item_corpus + gid * (D / 4);

    // Same d-ascending accumulation order as all passing rounds.
    f32x4 a0 = s_bp[0], a1 = s_bp[1], a2 = s_bp[2], a3 = s_bp[3];
    #pragma unroll 5
    for (int i = 0; i < D / 4; ++i) {
        f32x4 c = crow[i];
        #pragma unroll
        for (int dd = 0; dd < 4; ++dd) {
            float a = c[dd];
            const f32x4* wrow = &s_wp[(i * 4 + dd) * 4];
            a0 += a * wrow[0];
            a1 += a * wrow[1];
            a2 += a * wrow[2];
            a3 += a * wrow[3];
        }
    }
    f32x4* wout = (f32x4*)ic_ws + gid * 4;
    wout[0] = a0; wout[1] = a1; wout[2] = a2; wout[3] = a3;
}

// ================= Kernel B: greedy search =================
// 2 lanes/row. W_k promotion CONTROLLED (not prohibited like r8's volatile):
// per-k-chunk laundered LDS offsets stop CSE/LICM from keeping the whole
// 256-reg W_k tile live (r1-r7's spill cause), while in-chunk loads stay
// ordinary pipelined ds_read_b128 (r8's volatile serialized them).
__global__ __launch_bounds__(NT, 1)
void search_kernel(const float* __restrict__ user_intent,
                   const float* __restrict__ ic_ws,
                   const float* __restrict__ W_k,
                   const float* __restrict__ b_k,
                   float* __restrict__ out)
{
    __shared__ f32x4 s_wk[H * 4];       // wk[k][q]
    __shared__ f32x4 s_bk[4];
    __shared__ f32x4 s_out[RPB * RQ];   // 50 KB out staging
    {
        float* wkf = (float*)s_wk;
        for (int i = threadIdx.x; i < H * H; i += NT) wkf[i] = W_k[i];
        if (threadIdx.x < H) ((float*)s_bk)[threadIdx.x] = b_k[threadIdx.x];
    }
    __syncthreads();

    const int t = threadIdx.x;
    const int half = t & 1;
    const int r = t >> 1;
    const size_t b = (size_t)blockIdx.x * RPB + r;

    // Load this lane's 5 ic rows: 320B contiguous per lane, lines fully used.
    const f32x4* icin = (const f32x4*)ic_ws + (b * S + half * SL) * 4;
    f32x4 ic[SL][4];
    #pragma unroll
    for (int ls = 0; ls < SL; ++ls)
        #pragma unroll
        for (int q = 0; q < 4; ++q)
            ic[ls][q] = icin[ls * 4 + q];

    const f32x4* urow = (const f32x4*)user_intent + b * 4;
    f32x4 usum[4];
    #pragma unroll
    for (int q = 0; q < 4; ++q) {
        usum[q] = urow[q];
        if (!half) s_out[r * RQ + q] = usum[q];   // ui[:,0,:]
    }

    #pragma unroll 1
    for (int it = 0; it < NITER; ++it) {
        // ic = ic @ Wk + bk. k-chunks of 2 (8 w-quads live), each chunk's
        // wk reads amortized over all 5 local rows. Accumulation k-ascending
        // -> bit-identical to all passing rounds.
        f32x4 n[SL][4];
        #pragma unroll
        for (int ls = 0; ls < SL; ++ls)
            #pragma unroll
            for (int q = 0; q < 4; ++q) n[ls][q] = s_bk[q];

        #pragma unroll
        for (int kc = 0; kc < H / 2; ++kc) {
            int off = kc * 8;                    // quad index of wk[k=2*kc][0]
            asm volatile("" : "+v"(off));        // launder: kill cross-chunk CSE
            #pragma unroll
            for (int kk = 0; kk < 2; ++kk) {     // k = 2*kc + kk
                f32x4 w0 = s_wk[off + kk * 4 + 0];
                f32x4 w1 = s_wk[off + kk * 4 + 1];
                f32x4 w2 = s_wk[off + kk * 4 + 2];
                f32x4 w3 = s_wk[off + kk * 4 + 3];
                #pragma unroll
                for (int ls = 0; ls < SL; ++ls) {
                    const int k = kc * 2 + kk;
                    float a = ic[ls][k >> 2][k & 3];   // static indices
                    n[ls][0] += a * w0;
                    n[ls][1] += a * w1;
                    n[ls][2] += a * w2;
                    n[ls][3] += a * w3;
                }
            }
        }
        #pragma unroll
        for (int ls = 0; ls < SL; ++ls)
            #pragma unroll
            for (int q = 0; q < 4; ++q) ic[ls][q] = n[ls][q];

        float cnt = (float)(it + 1);
        f32x4 src[4];
        #pragma unroll
        for (int q = 0; q < 4; ++q) src[q] = usum[q] / cnt;

        // full per-row scores in one lane (q,c ascending -> bit-identical)
        float best = 0.0f;
        int gidx = half * SL;
        #pragma unroll
        for (int ls = 0; ls < SL; ++ls) {
            float sc = 0.0f;
            #pragma unroll
            for (int q = 0; q < 4; ++q)
                #pragma unroll
                for (int c = 0; c < 4; ++c)
                    sc += ic[ls][q][c] * src[q][c];
            if (ls == 0 || sc > best) { best = sc; gidx = half * SL + ls; }
        }

        // pair combine: low half wins ties (first-max over s)
        float osc = __shfl_xor(best, 1);
        int oidx = __shfl_xor(gidx, 1);
        float scL = half ? osc : best;
        int   iL  = half ? oidx : gidx;
        float scH = half ? best : osc;
        int   iH  = half ? gidx : oidx;
        int bidx = (scH > scL) ? iH : iL;

        // owner lane selects (static indexing); pair-sum broadcast (x+0 exact)
        f32x4 ivl[4];
        #pragma unroll
        for (int q = 0; q < 4; ++q) ivl[q] = f32x4{0.f, 0.f, 0.f, 0.f};
        #pragma unroll
        for (int ls = 0; ls < SL; ++ls) {
            bool take = ((half * SL + ls) == bidx);
            #pragma unroll
            for (int q = 0; q < 4; ++q)
                ivl[q] = take ? ic[ls][q] : ivl[q];
        }
        f32x4 iv[4];
        #pragma unroll
        for (int q = 0; q < 4; ++q) {
            #pragma unroll
            for (int c = 0; c < 4; ++c)
                iv[q][c] = ivl[q][c] + __shfl_xor(ivl[q][c], 1);
        }

        #pragma unroll
        for (int q = 0; q < 4; ++q) {
            usum[q] += iv[q];
            if (!half) s_out[r * RQ + (it + 1) * 4 + q] = iv[q];
        }
    }

    __syncthreads();
    f32x4* out4 = (f32x4*)out;
    const size_t obase = (size_t)blockIdx.x * RPB * OUTQ;
    #pragma unroll
    for (int k = 0; k < OUTQ / 2; ++k) {
        int j = t + k * NT;
        int row = j / OUTQ;
        int q = j - row * OUTQ;
        out4[obase + j] = s_out[row * RQ + q];
    }
}

// ================= Fallback: round-5 fused kernel =================
__global__ __launch_bounds__(NT, 1)
void fused_kernel(const float* __restrict__ user_intent,
                  const float* __restrict__ item_corpus,
                  const float* __restrict__ W_proj,
                  const float* __restrict__ b_proj,
                  const float* __restrict__ W_k,
                  const float* __restrict__ b_k,
                  float* __restrict__ out)
{
    __shared__ f32x4 s_wp[D * 4];
    __shared__ f32x4 s_wk[H * 4];
    __shared__ f32x4 s_bp[4];
    __shared__ f32x4 s_bk[4];
    __shared__ f32x4 s_out[NT * RQ];
    {
        float* wpf = (float*)s_wp;
        for (int i = threadIdx.x; i < D * H; i += NT) wpf[i] = W_proj[i];
        float* wkf = (float*)s_wk;
        for (int i = threadIdx.x; i < H * H; i += NT) wkf[i] = W_k[i];
        if (threadIdx.x < H) {
            ((float*)s_bp)[threadIdx.x] = b_proj[threadIdx.x];
            ((float*)s_bk)[threadIdx.x] = b_k[threadIdx.x];
        }
    }
    __syncthreads();

    const int t = threadIdx.x;
    const size_t b = (size_t)blockIdx.x * NT + t;
    const f32x4* crow = (const f32x4*)item_corpus + b * (S * D / 4);
    const f32x4* urow = (const f32x4*)user_intent + b * 4;
    f32x4 usum[4];
    #pragma unroll
    for (int q = 0; q < 4; ++q) {
        f32x4 u = urow[q];
        usum[q] = u;
        s_out[t * RQ + q] = u;
    }
    f32x4 ic[S][4];
    #pragma unroll
    for (int s = 0; s < S; ++s) {
        f32x4 a0 = s_bp[0], a1 = s_bp[1], a2 = s_bp[2], a3 = s_bp[3];
        #pragma unroll 5
        for (int i = 0; i < D / 4; ++i) {
            f32x4 c = crow[s * (D / 4) + i];
            #pragma unroll
            for (int dd = 0; dd < 4; ++dd) {
                float a = c[dd];
                const f32x4* wrow = &s_wp[(i * 4 + dd) * 4];
                a0 += a * wrow[0]; a1 += a * wrow[1];
                a2 += a * wrow[2]; a3 += a * wrow[3];
            }
        }
        ic[s][0] = a0; ic[s][1] = a1; ic[s][2] = a2; ic[s][3] = a3;
    }
    for (int it = 0; it < NITER; ++it) {
        #pragma unroll
        for (int s = 0; s < S; ++s) {
            f32x4 n0 = s_bk[0], n1 = s_bk[1], n2 = s_bk[2], n3 = s_bk[3];
            #pragma unroll
            for (int k = 0; k < H; ++k) {
                float a = ic[s][k >> 2][k & 3];
                const f32x4* wrow = &s_wk[k * 4];
                n0 += a * wrow[0]; n1 += a * wrow[1];
                n2 += a * wrow[2]; n3 += a * wrow[3];
            }
            ic[s][0] = n0; ic[s][1] = n1; ic[s][2] = n2; ic[s][3] = n3;
        }
        float cnt = (float)(it + 1);
        f32x4 src[4];
        #pragma unroll
        for (int q = 0; q < 4; ++q) src[q] = usum[q] / cnt;
        float best = 0.0f;
        int bidx = 0;
        #pragma unroll
        for (int s = 0; s < S; ++s) {
            float sc = 0.0f;
            #pragma unroll
            for (int q = 0; q < 4; ++q)
                #pragma unroll
                for (int c = 0; c < 4; ++c)
                    sc += ic[s][q][c] * src[q][c];
            if (s == 0 || sc > best) { best = sc; bidx = s; }
        }
        f32x4 iv[4];
        #pragma unroll
        for (int q = 0; q < 4; ++q) iv[q] = ic[0][q];
        #pragma unroll
        for (int s = 1; s < S; ++s) {
            bool take = (bidx == s);
            #pragma unroll
            for (int q = 0; q < 4; ++q)
                iv[q] = take ? ic[s][q] : iv[q];
        }
        #pragma unroll
        for (int q = 0; q < 4; ++q) {
            usum[q] += iv[q];
            s_out[t * RQ + (it + 1) * 4 + q] = iv[q];
        }
    }
    __syncthreads();
    f32x4* out4 = (f32x4*)out;
    const size_t obase = (size_t)blockIdx.x * NT * OUTQ;
    #pragma unroll
    for (int k = 0; k < OUTQ; ++k) {
        int j = t + k * NT;
        int row = j / OUTQ;
        int q = j - row * OUTQ;
        out4[obase + j] = s_out[row * RQ + q];
    }
}

extern "C" void kernel_launch(void* const* d_in, const int* in_sizes, int n_in,
                              void* d_out, int out_size, void* d_ws, size_t ws_size,
                              hipStream_t stream) {
    const float* user_intent = (const float*)d_in[0];
    const float* item_corpus = (const float*)d_in[1];
    const float* W_proj      = (const float*)d_in[2];
    const float* b_proj      = (const float*)d_in[3];
    const float* W_k         = (const float*)d_in[4];
    const float* b_k         = (const float*)d_in[5];
    float* out = (float*)d_out;
    const int bs = 65536;

    if (ws_size >= WS_NEEDED) {
        float* ic_ws = (float*)d_ws;
        hipLaunchKernelGGL(proj_kernel,
                           dim3(bs * S / NT), dim3(NT), 0, stream,
                           item_corpus, W_proj, b_proj, ic_ws);
        hipLaunchKernelGGL(search_kernel,
                           dim3(bs / RPB), dim3(NT), 0, stream,
                           user_intent, ic_ws, W_k, b_k, out);
    } else {
        hipLaunchKernelGGL(fused_kernel,
                           dim3(bs / NT), dim3(NT), 0, stream,
                           user_intent, item_corpus, W_proj, b_proj, W_k, b_k, out);
    }
}